// Round 1
// baseline (273.856 us; speedup 1.0000x reference)
//
#include <hip/hip_runtime.h>
#include <hip/hip_bf16.h>

typedef float  f32x4  __attribute__((ext_vector_type(4)));
typedef float  f4     __attribute__((ext_vector_type(4)));
typedef __bf16 bf16x8 __attribute__((ext_vector_type(8)));

#define GRID  512
#define ITERS 32   // GRID * ITERS * 16 rows = 262144

// exp_proj onto {sign(w) * 0.25 * 2^k, k=0..4}.
// Boundaries in |w|: 0.25*2^(k+0.5). Threshold-count == round(log2(|w|/0.25)) clipped.
__device__ __forceinline__ float qlog(float v) {
    float a = fabsf(v);
    int k = (a >= 0.35355339059327373f)
          + (a >= 0.70710678118654746f)
          + (a >= 1.41421356237309515f)
          + (a >= 2.82842712474619029f);
    float q = 0.25f * (float)(1 << k);
    return (v == 0.0f) ? 0.0f : copysignf(q, v);
}

__global__ __launch_bounds__(512, 2) void lqw_gemm(
    const float* __restrict__ in,    // [262144][256]
    const float* __restrict__ w,     // [256][256]  (out x in)
    const float* __restrict__ bias,  // [256]
    float* __restrict__ out)         // [262144][256]
{
    const int lane = threadIdx.x & 63;
    const int wv   = threadIdx.x >> 6;   // 0..7, owns 32 output cols
    const int nbase = wv * 32;
    const int lrow = lane & 15;          // A-row / B-col index within 16-tile
    const int kgrp = lane >> 4;          // 0..3
    const int k0   = kgrp * 8;           // 8 consecutive k per lane

    // ---- quantize weight slice into register-resident B fragments ----
    // B[k][n] = qlog(w[n][k]); lane holds n = nbase + t*16 + lrow, k = kt*32 + k0 + e
    bf16x8 bq[2][8];
    #pragma unroll
    for (int t = 0; t < 2; ++t) {
        const float* wrow = w + (nbase + t * 16 + lrow) * 256;
        #pragma unroll
        for (int kt = 0; kt < 8; ++kt) {
            f4 w0 = *(const f4*)(wrow + kt * 32 + k0);
            f4 w1 = *(const f4*)(wrow + kt * 32 + k0 + 4);
            bf16x8 fr;
            #pragma unroll
            for (int e = 0; e < 4; ++e) fr[e]     = (__bf16)qlog(w0[e]);
            #pragma unroll
            for (int e = 0; e < 4; ++e) fr[4 + e] = (__bf16)qlog(w1[e]);
            bq[t][kt] = fr;
        }
    }
    float bs[2];
    #pragma unroll
    for (int t = 0; t < 2; ++t) bs[t] = bias[nbase + t * 16 + lrow];

    // ---- prologue: load first A tile (16 rows x 256 k, this lane's 8-k slice) ----
    int mt = blockIdx.x;
    f4 r[16];
    {
        const float* arow = in + (mt * 16 + lrow) * 256 + k0;
        #pragma unroll
        for (int kt = 0; kt < 8; ++kt) {
            r[2 * kt]     = *(const f4*)(arow + kt * 32);
            r[2 * kt + 1] = *(const f4*)(arow + kt * 32 + 4);
        }
    }

    for (int it = 0; it < ITERS; ++it) {
        // convert current raw A to bf16 fragments (frees r for prefetch)
        bf16x8 a[8];
        #pragma unroll
        for (int kt = 0; kt < 8; ++kt) {
            bf16x8 fr;
            #pragma unroll
            for (int e = 0; e < 4; ++e) fr[e]     = (__bf16)r[2 * kt][e];
            #pragma unroll
            for (int e = 0; e < 4; ++e) fr[4 + e] = (__bf16)r[2 * kt + 1][e];
            a[kt] = fr;
        }

        // prefetch next m-tile
        const int mt_n = mt + GRID;
        if (it + 1 < ITERS) {
            const float* arow = in + (mt_n * 16 + lrow) * 256 + k0;
            #pragma unroll
            for (int kt = 0; kt < 8; ++kt) {
                r[2 * kt]     = *(const f4*)(arow + kt * 32);
                r[2 * kt + 1] = *(const f4*)(arow + kt * 32 + 4);
            }
        }

        // MFMA: acc init with bias (col = lane&15 fixed per lane)
        f32x4 acc[2];
        #pragma unroll
        for (int t = 0; t < 2; ++t) acc[t] = (f32x4){bs[t], bs[t], bs[t], bs[t]};
        #pragma unroll
        for (int kt = 0; kt < 8; ++kt)
            #pragma unroll
            for (int t = 0; t < 2; ++t)
                acc[t] = __builtin_amdgcn_mfma_f32_16x16x32_bf16(a[kt], bq[t][kt], acc[t], 0, 0, 0);

        // store: D row = kgrp*4 + reg, col = nbase + t*16 + lrow
        float* orow = out + (mt * 16 + kgrp * 4) * 256 + nbase + lrow;
        #pragma unroll
        for (int t = 0; t < 2; ++t)
            #pragma unroll
            for (int rg = 0; rg < 4; ++rg)
                orow[rg * 256 + t * 16] = acc[t][rg];

        mt = mt_n;
    }
}

extern "C" void kernel_launch(void* const* d_in, const int* in_sizes, int n_in,
                              void* d_out, int out_size, void* d_ws, size_t ws_size,
                              hipStream_t stream) {
    const float* in_p   = (const float*)d_in[0];
    const float* w_p    = (const float*)d_in[1];
    const float* bias_p = (const float*)d_in[2];
    float* out_p        = (float*)d_out;
    lqw_gemm<<<GRID, 512, 0, stream>>>(in_p, w_p, bias_p, out_p);
}

// Round 2
// 178.949 us; speedup vs baseline: 1.5304x; 1.5304x over previous
//
#include <hip/hip_runtime.h>
#include <hip/hip_bf16.h>
#include <stdint.h>

typedef float  f32x4  __attribute__((ext_vector_type(4)));
typedef __bf16 bf16x8 __attribute__((ext_vector_type(8)));
typedef __bf16 bf16x4 __attribute__((ext_vector_type(4)));

#define GRID   512
#define MROWS  32
#define ITERS  16          // GRID * ITERS * MROWS = 262144 rows
#define ROWB   528         // bf16 LDS row stride in bytes (512 + 16 pad)
#define TILEB  (MROWS * ROWB)

// exp_proj onto {sign(w) * 0.25 * 2^k, k=0..4}; boundaries at 0.25*2^(k+0.5)
__device__ __forceinline__ float qlog(float v) {
    float a = fabsf(v);
    int k = (a >= 0.35355339059327373f)
          + (a >= 0.70710678118654746f)
          + (a >= 1.41421356237309515f)
          + (a >= 2.82842712474619029f);
    float q = 0.25f * (float)(1 << k);
    return (v == 0.0f) ? 0.0f : copysignf(q, v);
}

__global__ __launch_bounds__(512, 4) void lqw_gemm(
    const float* __restrict__ in,    // [262144][256]
    const float* __restrict__ w,     // [256][256]
    const float* __restrict__ bias,  // [256]
    float* __restrict__ out)         // [262144][256]
{
    __shared__ __align__(16) char smem[2 * TILEB];   // 33792 B
    const int tid  = threadIdx.x;
    const int lane = tid & 63;
    const int wv   = tid >> 6;       // wave 0..7 owns 32 output cols
    const int nbase = wv * 32;
    const int lrow = lane & 15;
    const int kgrp = lane >> 4;
    const int k0   = kgrp * 8;

    // ---- register-resident quantized B fragments (one-time, L2-served) ----
    bf16x8 bq[2][8];
    #pragma unroll
    for (int nt = 0; nt < 2; ++nt) {
        const float* wrow = w + (size_t)(nbase + nt * 16 + lrow) * 256;
        #pragma unroll
        for (int kt = 0; kt < 8; ++kt) {
            bf16x8 fr;
            #pragma unroll
            for (int e = 0; e < 8; ++e) fr[e] = (__bf16)qlog(wrow[kt * 32 + k0 + e]);
            bq[nt][kt] = fr;
        }
    }
    float bs[2] = { bias[nbase + lrow], bias[nbase + 16 + lrow] };

    const int mt0 = blockIdx.x * ITERS;
    f32x4 sreg[4];

    // coalesced tile load: instr r covers one contiguous 8 KB slab
    #define LOAD_TILE(mt) do {                                             \
        const f32x4* _s = (const f32x4*)(in + (size_t)(mt) * (MROWS*256)); \
        sreg[0] = _s[0*512 + tid]; sreg[1] = _s[1*512 + tid];              \
        sreg[2] = _s[2*512 + tid]; sreg[3] = _s[3*512 + tid];              \
    } while (0)

    // cvt to bf16 + conflict-free row-contiguous ds_write_b64
    #define WRITE_TILE(b) do {                                             \
        char* _d = smem + (b) * TILEB;                                     \
        _Pragma("unroll")                                                  \
        for (int r = 0; r < 4; ++r) {                                      \
            int j = r * 512 + tid;          /* f4 index in 32x256 tile */  \
            bf16x4 v;                                                      \
            v[0] = (__bf16)sreg[r][0]; v[1] = (__bf16)sreg[r][1];          \
            v[2] = (__bf16)sreg[r][2]; v[3] = (__bf16)sreg[r][3];          \
            *(bf16x4*)(_d + (j >> 6) * ROWB + (j & 63) * 8) = v;           \
        }                                                                  \
    } while (0)

    LOAD_TILE(mt0);
    WRITE_TILE(0);
    LOAD_TILE(mt0 + 1);
    __syncthreads();

    for (int t = 0; t < ITERS; ++t) {
        const int b = t & 1;
        if (t + 1 < ITERS) WRITE_TILE(b ^ 1);          // stage tile t+1
        if (t + 2 < ITERS) LOAD_TILE(mt0 + t + 2);     // prefetch tile t+2

        const char* base = smem + b * TILEB;
        f32x4 acc[2][2];
        #pragma unroll
        for (int mi = 0; mi < 2; ++mi)
            #pragma unroll
            for (int nt = 0; nt < 2; ++nt)
                acc[mi][nt] = (f32x4){bs[nt], bs[nt], bs[nt], bs[nt]};

        #pragma unroll
        for (int kt = 0; kt < 8; ++kt) {
            bf16x8 a0 = *(const bf16x8*)(base + (size_t)lrow * ROWB + kt * 64 + kgrp * 16);
            bf16x8 a1 = *(const bf16x8*)(base + (size_t)(16 + lrow) * ROWB + kt * 64 + kgrp * 16);
            acc[0][0] = __builtin_amdgcn_mfma_f32_16x16x32_bf16(a0, bq[0][kt], acc[0][0], 0, 0, 0);
            acc[0][1] = __builtin_amdgcn_mfma_f32_16x16x32_bf16(a0, bq[1][kt], acc[0][1], 0, 0, 0);
            acc[1][0] = __builtin_amdgcn_mfma_f32_16x16x32_bf16(a1, bq[0][kt], acc[1][0], 0, 0, 0);
            acc[1][1] = __builtin_amdgcn_mfma_f32_16x16x32_bf16(a1, bq[1][kt], acc[1][1], 0, 0, 0);
        }

        const int mt = mt0 + t;
        #pragma unroll
        for (int mi = 0; mi < 2; ++mi) {
            float* orow = out + (size_t)(mt * 32 + mi * 16 + kgrp * 4) * 256 + nbase + lrow;
            #pragma unroll
            for (int nt = 0; nt < 2; ++nt)
                #pragma unroll
                for (int rg = 0; rg < 4; ++rg)
                    orow[(size_t)rg * 256 + nt * 16] = acc[mi][nt][rg];
        }
        __syncthreads();
    }
}

extern "C" void kernel_launch(void* const* d_in, const int* in_sizes, int n_in,
                              void* d_out, int out_size, void* d_ws, size_t ws_size,
                              hipStream_t stream) {
    const float* in_p   = (const float*)d_in[0];
    const float* w_p    = (const float*)d_in[1];
    const float* bias_p = (const float*)d_in[2];
    float* out_p        = (float*)d_out;
    lqw_gemm<<<GRID, 512, 0, stream>>>(in_p, w_p, bias_p, out_p);
}

// Round 3
// 175.695 us; speedup vs baseline: 1.5587x; 1.0185x over previous
//
#include <hip/hip_runtime.h>
#include <hip/hip_bf16.h>
#include <stdint.h>

typedef float  f32x4  __attribute__((ext_vector_type(4)));
typedef __bf16 bf16x8 __attribute__((ext_vector_type(8)));
typedef __bf16 bf16x4 __attribute__((ext_vector_type(4)));

#define GRID   512
#define MROWS  32
#define ITERS  16          // GRID * ITERS * MROWS = 262144 rows
#define ROWB   528         // bf16 LDS row stride in bytes (512 + 16 pad)
#define TILEB  (MROWS * ROWB)

// exp_proj onto {sign(w) * 0.25 * 2^k, k=0..4}; boundaries at 0.25*2^(k+0.5)
__device__ __forceinline__ float qlog(float v) {
    float a = fabsf(v);
    int k = (a >= 0.35355339059327373f)
          + (a >= 0.70710678118654746f)
          + (a >= 1.41421356237309515f)
          + (a >= 2.82842712474619029f);
    float q = 0.25f * (float)(1 << k);
    return (v == 0.0f) ? 0.0f : copysignf(q, v);
}

__global__ __launch_bounds__(512, 4) void lqw_gemm(
    const float* __restrict__ in,    // [262144][256]
    const float* __restrict__ w,     // [256][256]
    const float* __restrict__ bias,  // [256]
    float* __restrict__ out)         // [262144][256]
{
    __shared__ __align__(16) char smem[2 * TILEB];   // 33792 B
    const int tid  = threadIdx.x;
    const int lane = tid & 63;
    const int wv   = tid >> 6;       // wave 0..7 owns 32 output cols
    const int nbase = wv * 32;
    const int lrow = lane & 15;
    const int kgrp = lane >> 4;
    const int k0   = kgrp * 8;

    // ---- register-resident quantized B fragments (one-time, L2-served) ----
    // lane holds n = nbase + nt*16 + lrow, k = kt*32 + k0 + e  (A-operand layout)
    bf16x8 bq[2][8];
    #pragma unroll
    for (int nt = 0; nt < 2; ++nt) {
        const float* wrow = w + (size_t)(nbase + nt * 16 + lrow) * 256;
        #pragma unroll
        for (int kt = 0; kt < 8; ++kt) {
            bf16x8 fr;
            #pragma unroll
            for (int e = 0; e < 8; ++e) fr[e] = (__bf16)qlog(wrow[kt * 32 + k0 + e]);
            bq[nt][kt] = fr;
        }
    }
    // bias vector for swapped-D layout: lane holds n = nbase + nt*16 + kgrp*4 + rg
    f32x4 bv[2];
    #pragma unroll
    for (int nt = 0; nt < 2; ++nt)
        bv[nt] = *(const f32x4*)(bias + nbase + nt * 16 + kgrp * 4);

    const int mt0 = blockIdx.x * ITERS;
    f32x4 sreg[4];

    // coalesced tile load: instr r covers one contiguous 8 KB slab
    #define LOAD_TILE(mt) do {                                             \
        const f32x4* _s = (const f32x4*)(in + (size_t)(mt) * (MROWS*256)); \
        sreg[0] = _s[0*512 + tid]; sreg[1] = _s[1*512 + tid];              \
        sreg[2] = _s[2*512 + tid]; sreg[3] = _s[3*512 + tid];              \
    } while (0)

    // cvt to bf16 + conflict-free row-contiguous ds_write_b64
    #define WRITE_TILE(b) do {                                             \
        char* _d = smem + (b) * TILEB;                                     \
        _Pragma("unroll")                                                  \
        for (int r = 0; r < 4; ++r) {                                      \
            int j = r * 512 + tid;          /* f4 index in 32x256 tile */  \
            bf16x4 v;                                                      \
            v[0] = (__bf16)sreg[r][0]; v[1] = (__bf16)sreg[r][1];          \
            v[2] = (__bf16)sreg[r][2]; v[3] = (__bf16)sreg[r][3];          \
            *(bf16x4*)(_d + (j >> 6) * ROWB + (j & 63) * 8) = v;           \
        }                                                                  \
    } while (0)

    LOAD_TILE(mt0);
    WRITE_TILE(0);
    LOAD_TILE(mt0 + 1);
    __syncthreads();

    for (int t = 0; t < ITERS; ++t) {
        const int b = t & 1;
        if (t + 1 < ITERS) WRITE_TILE(b ^ 1);          // stage tile t+1
        if (t + 2 < ITERS) LOAD_TILE(mt0 + t + 2);     // prefetch tile t+2

        const char* base = smem + b * TILEB;
        f32x4 acc[2][2];
        #pragma unroll
        for (int mi = 0; mi < 2; ++mi)
            #pragma unroll
            for (int nt = 0; nt < 2; ++nt)
                acc[mi][nt] = bv[nt];

        #pragma unroll
        for (int kt = 0; kt < 8; ++kt) {
            bf16x8 a0 = *(const bf16x8*)(base + (size_t)lrow * ROWB + kt * 64 + kgrp * 16);
            bf16x8 a1 = *(const bf16x8*)(base + (size_t)(16 + lrow) * ROWB + kt * 64 + kgrp * 16);
            // swapped operands: D[i=n][j=m] -> lane holds 4 consecutive n
            acc[0][0] = __builtin_amdgcn_mfma_f32_16x16x32_bf16(bq[0][kt], a0, acc[0][0], 0, 0, 0);
            acc[0][1] = __builtin_amdgcn_mfma_f32_16x16x32_bf16(bq[1][kt], a0, acc[0][1], 0, 0, 0);
            acc[1][0] = __builtin_amdgcn_mfma_f32_16x16x32_bf16(bq[0][kt], a1, acc[1][0], 0, 0, 0);
            acc[1][1] = __builtin_amdgcn_mfma_f32_16x16x32_bf16(bq[1][kt], a1, acc[1][1], 0, 0, 0);
        }

        // store: row m = mt*32 + mi*16 + lrow, cols nbase + nt*16 + kgrp*4 .. +3
        const int mt = mt0 + t;
        #pragma unroll
        for (int mi = 0; mi < 2; ++mi) {
            float* orow = out + (size_t)(mt * 32 + mi * 16 + lrow) * 256 + nbase + kgrp * 4;
            #pragma unroll
            for (int nt = 0; nt < 2; ++nt)
                __builtin_nontemporal_store(acc[mi][nt], (f32x4*)(orow + nt * 16));
        }
        __syncthreads();
    }
}

extern "C" void kernel_launch(void* const* d_in, const int* in_sizes, int n_in,
                              void* d_out, int out_size, void* d_ws, size_t ws_size,
                              hipStream_t stream) {
    const float* in_p   = (const float*)d_in[0];
    const float* w_p    = (const float*)d_in[1];
    const float* bias_p = (const float*)d_in[2];
    float* out_p        = (float*)d_out;
    lqw_gemm<<<GRID, 512, 0, stream>>>(in_p, w_p, bias_p, out_p);
}